// Round 1
// baseline (521.781 us; speedup 1.0000x reference)
//
#include <hip/hip_runtime.h>
#include <math.h>

#define LSEQ 2048
#define NB 2
#define HDIM 1024
#define NKV 128          // 2*HEAD_SIZE
#define MALL (NB*LSEQ)   // 4096
#define KSPLIT 4

// ---------------- K1: seq_out partials = inputs @ Wp (K split in 4) --------
// grid (8, 64): x = nt(2) + 2*split(4), y = m-tile. 256 threads, 64x64 tile,
// micro 4x4 per thread, K-chunk 32, 8 chunks per split.
__global__ __launch_bounds__(256) void k1_gemm(const float* __restrict__ A,
                                               const float* __restrict__ Wp,
                                               float* __restrict__ Cp) {
    const int nt    = blockIdx.x & 1;
    const int split = blockIdx.x >> 1;
    const int m0 = blockIdx.y * 64;
    const int n0 = nt * 64;
    __shared__ float As[32][68];   // [k][m], pad 68 keeps float4 reads 16B-aligned
    __shared__ float Bs[32][64];   // [k][n]
    const int tid = threadIdx.x;
    const int tm = tid & 15;       // m quad
    const int tn = tid >> 4;       // n quad
    float acc[4][4] = {};
    for (int kc = 0; kc < 8; ++kc) {
        const int k0 = split*256 + kc*32;
        #pragma unroll
        for (int p = 0; p < 2; ++p) {
            int idx = tid + 256*p;          // 0..511
            int row = idx >> 3, kq = idx & 7;
            float4 a = *(const float4*)(A + (size_t)(m0+row)*HDIM + k0 + 4*kq);
            As[4*kq+0][row] = a.x;
            As[4*kq+1][row] = a.y;
            As[4*kq+2][row] = a.z;
            As[4*kq+3][row] = a.w;
        }
        #pragma unroll
        for (int p = 0; p < 2; ++p) {
            int idx = tid + 256*p;
            int r = idx >> 4, c = idx & 15;
            *(float4*)(&Bs[r][4*c]) = *(const float4*)(Wp + (size_t)(k0+r)*NKV + n0 + 4*c);
        }
        __syncthreads();
        #pragma unroll
        for (int kk = 0; kk < 32; ++kk) {
            float4 av = *(const float4*)(&As[kk][4*tm]);
            float4 bv = *(const float4*)(&Bs[kk][4*tn]);
            float aa[4] = {av.x, av.y, av.z, av.w};
            float bb[4] = {bv.x, bv.y, bv.z, bv.w};
            #pragma unroll
            for (int i = 0; i < 4; ++i)
                #pragma unroll
                for (int j = 0; j < 4; ++j)
                    acc[i][j] = fmaf(aa[i], bb[j], acc[i][j]);
        }
        __syncthreads();
    }
    float* outp = Cp + (size_t)split*MALL*NKV;
    #pragma unroll
    for (int i = 0; i < 4; ++i) {
        float4 v = make_float4(acc[i][0], acc[i][1], acc[i][2], acc[i][3]);
        *(float4*)(outp + (size_t)(m0 + 4*tm + i)*NKV + n0 + 4*tn) = v;
    }
}

// ---------------- K2: sum K-splits (+bp), RoPE, bias = seq@Wq/2 ------------
// grid 4096 blocks x 64 threads (1 wave per row).
__global__ __launch_bounds__(64) void k2_rope_bias(const float* __restrict__ Cp,
        const float* __restrict__ bp, const float* __restrict__ Wq,
        const float* __restrict__ bq, float* __restrict__ qwout,
        float* __restrict__ kwout, float* __restrict__ biasQ,
        float* __restrict__ biasK) {
    const int row = blockIdx.x;         // 0..4095 (b*L + l)
    const int b = row >> 11;
    const int l = row & (LSEQ - 1);
    const int t = threadIdx.x;          // 0..63 ; lane t owns dims (2t, 2t+1)
    float x0 = bp[2*t], x1 = bp[2*t+1];
    #pragma unroll
    for (int s = 0; s < KSPLIT; ++s) {
        const float* r = Cp + (size_t)s*MALL*NKV + (size_t)row*NKV;
        x0 += r[2*t];
        x1 += r[2*t+1];
    }
    // RoPE: lanes 0..31 -> q (dims 0..63), lanes 32..63 -> k (dims 64..127)
    const int p = t & 31;               // pair index within head
    float inv = exp2f(-0.41524101186098287f * (float)p);  // 10000^(-p/32)
    float ang = (float)l * inv;
    float sn = sinf(ang), cs = cosf(ang);
    float y0 = x0*cs - x1*sn;
    float y1 = x1*cs + x0*sn;
    float* dst = (t < 32) ? (qwout + (size_t)row*64) : (kwout + (size_t)row*64);
    dst[2*p]   = y0;
    dst[2*p+1] = y1;
    // bias: 24 dot-products of (pre-RoPE) row with Wq columns, wave-reduced
    float res = 0.f;
    for (int j = 0; j < 24; ++j) {
        float part = fmaf(x0, Wq[(2*t)*24 + j], x1 * Wq[(2*t+1)*24 + j]);
        #pragma unroll
        for (int off = 32; off > 0; off >>= 1)
            part += __shfl_xor(part, off);
        if (t == j) res = part;
    }
    if (t < 24) {
        float v = (res + bq[t]) * 0.5f;
        int h = t >> 1;
        float* bb = (t & 1) ? biasK : biasQ;
        bb[((size_t)b*12 + h)*LSEQ + l] = v;
    }
}

// ---------------- K3 v3: write-BW-bound scores + 12-head fan-out -----------
// grid (256, 2): x = m-tile (8 rows), y = b. 512 threads = 8 waves.
// Wave w owns row m0+w (q wave-uniform in 64 VGPRs). n processed in 8 stages
// of 256, kw chunk double-buffered in 128 KB LDS with XOR-swizzled d-quads
// (quad ^= (row>>2)&7): conflict-free for both the coalesced staging writes
// and the per-lane 4-row ds_read_b128 dot reads. Lane owns 4 consecutive n
// -> float4 PLAIN stores (1 KB/wave/instr, the fillBuffer-proven pattern).
// One raw s_barrier + lgkmcnt(0) per stage: stores are never drained in-loop.
__global__ __launch_bounds__(512, 2) void k3_scores(const float* __restrict__ qw,
        const float* __restrict__ kwv, const float* __restrict__ biasQ,
        const float* __restrict__ biasK, const int* __restrict__ mask,
        float* __restrict__ out) {
    extern __shared__ float kws[];          // 2 * 16384 floats (128 KB)
    const int m0  = blockIdx.x * 8;
    const int b   = blockIdx.y;
    const int tid = threadIdx.x;
    const int w   = tid >> 6;               // wave id -> m row
    const int l   = tid & 63;               // lane -> n quad (4*l .. 4*l+3)
    const size_t rowbase = (size_t)b * LSEQ;
    const int m = m0 + w;
    const int swz = l & 7;

    // q row (wave-uniform address -> broadcast loads)
    float4 q4[16];
    {
        const float4* qp = (const float4*)(qw + (rowbase + m)*64);
        #pragma unroll
        for (int j = 0; j < 16; ++j) q4[j] = qp[j];
    }
    // per-head row biases (wave-uniform)
    float bqh[12];
    #pragma unroll
    for (int h = 0; h < 12; ++h) bqh[h] = biasQ[((size_t)b*12 + h)*LSEQ + m];
    const bool okm = mask[rowbase + m] != 0;
    const size_t outrow = (size_t)b*12*LSEQ*LSEQ + (size_t)m*LSEQ;

    // prolog: stage chunk 0 into buf 0 (coalesced loads, swizzled LDS writes)
    #pragma unroll
    for (int p = 0; p < 8; ++p) {
        int F = tid + 512*p;                // float4 index in 256x64 chunk
        int r = F >> 4, qd = F & 15;
        float4 v = *(const float4*)(kwv + (rowbase + r)*64 + 4*qd);
        *(float4*)(&kws[r*64 + 4*(qd ^ ((r>>2)&7))]) = v;
    }
    asm volatile("s_waitcnt lgkmcnt(0)" ::: "memory");
    __builtin_amdgcn_s_barrier();
    asm volatile("" ::: "memory");

    for (int s = 0; s < 8; ++s) {
        const int cur = (s & 1) * 16384;
        const int nxt = ((s + 1) & 1) * 16384;
        const bool more = (s + 1) < 8;

        // issue next chunk's global loads early (latency hides under compute)
        float4 pre[8];
        if (more) {
            const int n1 = (s + 1) * 256;
            #pragma unroll
            for (int p = 0; p < 8; ++p) {
                int F = tid + 512*p;
                int r = F >> 4, qd = F & 15;
                pre[p] = *(const float4*)(kwv + (rowbase + n1 + r)*64 + 4*qd);
            }
        }

        // dot: q[m] . kw[4l..4l+3] from swizzled LDS
        float acc0 = 0.f, acc1 = 0.f, acc2 = 0.f, acc3 = 0.f;
        const float* kb = kws + cur + 256*l;   // word base of row 4l
        #pragma unroll
        for (int j = 0; j < 16; ++j) {
            const int qo = 4*(j ^ swz);
            float4 k0 = *(const float4*)(kb + qo);
            float4 k1 = *(const float4*)(kb + 64 + qo);
            float4 k2 = *(const float4*)(kb + 128 + qo);
            float4 k3 = *(const float4*)(kb + 192 + qo);
            float4 qv = q4[j];
            acc0 = fmaf(qv.x,k0.x,fmaf(qv.y,k0.y,fmaf(qv.z,k0.z,fmaf(qv.w,k0.w,acc0))));
            acc1 = fmaf(qv.x,k1.x,fmaf(qv.y,k1.y,fmaf(qv.z,k1.z,fmaf(qv.w,k1.w,acc1))));
            acc2 = fmaf(qv.x,k2.x,fmaf(qv.y,k2.y,fmaf(qv.z,k2.z,fmaf(qv.w,k2.w,acc2))));
            acc3 = fmaf(qv.x,k3.x,fmaf(qv.y,k3.y,fmaf(qv.z,k3.z,fmaf(qv.w,k3.w,acc3))));
        }

        // mask + causal penalty, then 12-head fan-out with float4 stores
        const int nq = s*256 + 4*l;
        int4 mq = *(const int4*)(mask + rowbase + nq);
        float t0 = (okm && mq.x) ? fmaf(acc0, 0.125f, (m > nq+0) ? -1e12f : 0.f) : -INFINITY;
        float t1 = (okm && mq.y) ? fmaf(acc1, 0.125f, (m > nq+1) ? -1e12f : 0.f) : -INFINITY;
        float t2 = (okm && mq.z) ? fmaf(acc2, 0.125f, (m > nq+2) ? -1e12f : 0.f) : -INFINITY;
        float t3 = (okm && mq.w) ? fmaf(acc3, 0.125f, (m > nq+3) ? -1e12f : 0.f) : -INFINITY;
        const float* bkbase = biasK + (size_t)b*12*LSEQ + nq;
        float* op = out + outrow + nq;
        #pragma unroll
        for (int h = 0; h < 12; ++h) {
            float4 bk = *(const float4*)(bkbase + (size_t)h*LSEQ);
            float bq = bqh[h];
            float4 v;
            v.x = t0 + bq + bk.x;
            v.y = t1 + bq + bk.y;
            v.z = t2 + bq + bk.z;
            v.w = t3 + bq + bk.w;
            *(float4*)(op + (size_t)h*LSEQ*LSEQ) = v;
        }

        // write next chunk to the other LDS buffer, then one barrier
        if (more) {
            #pragma unroll
            for (int p = 0; p < 8; ++p) {
                int F = tid + 512*p;
                int r = F >> 4, qd = F & 15;
                *(float4*)(&kws[nxt + r*64 + 4*(qd ^ ((r>>2)&7))]) = pre[p];
            }
            asm volatile("s_waitcnt lgkmcnt(0)" ::: "memory");
            __builtin_amdgcn_s_barrier();
            asm volatile("" ::: "memory");
        }
    }
}

extern "C" void kernel_launch(void* const* d_in, const int* in_sizes, int n_in,
                              void* d_out, int out_size, void* d_ws, size_t ws_size,
                              hipStream_t stream) {
    const float* inputs = (const float*)d_in[0];   // (2,2048,1024)
    const int*   mask   = (const int*)  d_in[1];   // (2,2048)
    const float* Wp     = (const float*)d_in[2];   // (1024,128)
    const float* bp     = (const float*)d_in[3];   // (128,)
    const float* Wq     = (const float*)d_in[4];   // (128,24)
    const float* bq     = (const float*)d_in[5];   // (24,)
    float* out = (float*)d_out;                    // (2,12,2048,2048)

    float* Cp  = (float*)d_ws;                     // KSPLIT * 4096 * 128
    float* qwb = Cp  + (size_t)KSPLIT*MALL*NKV;    // 4096 * 64
    float* kwb = qwb + (size_t)MALL*64;            // 4096 * 64
    float* bQ  = kwb + (size_t)MALL*64;            // 2*12*2048
    float* bK  = bQ  + (size_t)NB*12*LSEQ;         // 2*12*2048

    k1_gemm     <<<dim3(8, 64),   256, 0, stream>>>(inputs, Wp, Cp);
    k2_rope_bias<<<dim3(MALL),     64, 0, stream>>>(Cp, bp, Wq, bq, qwb, kwb, bQ, bK);
    k3_scores   <<<dim3(256, 2), 512, 131072, stream>>>(qwb, kwb, bQ, bK, mask, out);
}